// Round 8
// baseline (847.142 us; speedup 1.0000x reference)
//
#include <hip/hip_runtime.h>
#include <math.h>

#define N_NODES 50000
#define M_PAD   50048   // 391 * 128
#define N_EDGES 800000
#define HID 512

typedef short bf16x8 __attribute__((ext_vector_type(8)));
typedef float f32x4  __attribute__((ext_vector_type(4)));
typedef unsigned short u16x4 __attribute__((ext_vector_type(4)));
typedef unsigned short u16x8 __attribute__((ext_vector_type(8)));

__device__ inline float b2f(unsigned short u) {
    union { unsigned int i; float f; } v; v.i = ((unsigned int)u) << 16; return v.f;
}
__device__ inline unsigned short f2b(float f) {
    union { float f; unsigned int i; } v; v.f = f;
    unsigned int r = v.i + 0x7FFFu + ((v.i >> 16) & 1u);
    return (unsigned short)(r >> 16);
}

// ---------------- CSR build ----------------

__global__ void zero_kernel(int* __restrict__ p, int n) {
    int i = blockIdx.x * blockDim.x + threadIdx.x;
    if (i < n) p[i] = 0;
}

__global__ void detect_kernel(const int* __restrict__ e, int* __restrict__ flag) {
    if (blockIdx.x == 0 && threadIdx.x == 0) {
        int is64 = 1;
        for (int i = 0; i < 16; ++i)
            if (e[2 * i + 1] != 0) is64 = 0;
        *flag = is64;
    }
}

__global__ void hist_kernel(const void* __restrict__ eidx, const int* __restrict__ flag,
                            int* __restrict__ counts) {
    int e = blockIdx.x * blockDim.x + threadIdx.x;
    if (e >= N_EDGES) return;
    int is64 = *flag;
    int d;
    if (is64) d = (int)((const long long*)eidx)[N_EDGES + e];
    else      d = ((const int*)eidx)[N_EDGES + e];
    atomicAdd(&counts[d], 1);
}

__global__ __launch_bounds__(1024) void scan_kernel(const int* __restrict__ counts,
                                                    int* __restrict__ offsets) {
    __shared__ int sums[1024];
    int t = threadIdx.x;
    const int CH = (N_NODES + 1023) / 1024;  // 49
    int lo = t * CH;
    int hi = min(lo + CH, N_NODES);
    int s = 0;
    for (int i = lo; i < hi; ++i) s += counts[i];
    sums[t] = s;
    __syncthreads();
    for (int off = 1; off < 1024; off <<= 1) {
        int v = 0;
        if (t >= off) v = sums[t - off];
        __syncthreads();
        sums[t] += v;
        __syncthreads();
    }
    int excl = (t == 0) ? 0 : sums[t - 1];
    for (int i = lo; i < hi; ++i) { offsets[i] = excl; excl += counts[i]; }
    if (t == 1023) offsets[N_NODES] = excl;
}

__global__ void fill_kernel(const void* __restrict__ eidx, const int* __restrict__ flag,
                            const int* __restrict__ offsets, int* __restrict__ cursor,
                            int* __restrict__ edge_src) {
    int e = blockIdx.x * blockDim.x + threadIdx.x;
    if (e >= N_EDGES) return;
    int is64 = *flag;
    int s, d;
    if (is64) {
        const long long* p = (const long long*)eidx;
        s = (int)p[e];
        d = (int)p[N_EDGES + e];
    } else {
        const int* p = (const int*)eidx;
        s = p[e];
        d = p[N_EDGES + e];
    }
    int pos = atomicAdd(&cursor[d], 1);
    edge_src[offsets[d] + pos] = s;
}

// ---------------- conversions ----------------

// x (f32 [N,256]) -> bf16 into feat-half of Cat1 ([M][512], cols 256..512)
__global__ __launch_bounds__(256) void xconv_kernel(const float* __restrict__ x,
                                                    unsigned short* __restrict__ cat1) {
    int id = blockIdx.x * 256 + threadIdx.x;
    if (id >= M_PAD * 64) return;
    int row = id >> 6;
    int c = (id & 63) * 4;
    float4 v = make_float4(0.f, 0.f, 0.f, 0.f);
    if (row < N_NODES) v = *(const float4*)(x + (size_t)row * 256 + c);
    ushort4 h;
    h.x = f2b(v.x); h.y = f2b(v.y); h.z = f2b(v.z); h.w = f2b(v.w);
    *(ushort4*)(cat1 + (size_t)row * 512 + 256 + c) = h;
}

// W (f32 [K,512]) -> transposed bf16 into Wcat[n][off + k], row stride ktot
__global__ __launch_bounds__(128) void wconv_kernel(const float* __restrict__ W,
                                                    unsigned short* __restrict__ T,
                                                    int K, int ktot, int off) {
    int n = blockIdx.x;  // 0..511
    for (int k = threadIdx.x; k < K; k += 128)
        T[(size_t)n * ktot + off + k] = f2b(W[(size_t)k * HID + n]);
}

// ---------------- aggregate: wave-per-node, 4 independent chains ----------------
// Feat width W = EPL*64, row stride 2W (halves of the concat plane).

template <int EPL>
__global__ __launch_bounds__(256) void aggregate_kernel(const unsigned short* __restrict__ Fh,
                                                        const int* __restrict__ off,
                                                        const int* __restrict__ esrc,
                                                        unsigned short* __restrict__ Ah) {
    const int W = EPL * 64;
    const int STRIDE = 2 * W;
    const int wid = threadIdx.x >> 6;
    const int lane = threadIdx.x & 63;
    const int node = blockIdx.x * 4 + wid;
    if (node >= N_NODES) return;
    const int beg = off[node], end = off[node + 1];
    const int deg = end - beg;

    float a0[EPL], a1[EPL], a2[EPL], a3[EPL];
#pragma unroll
    for (int j = 0; j < EPL; ++j) { a0[j] = 0.f; a1[j] = 0.f; a2[j] = 0.f; a3[j] = 0.f; }

    const int lb = lane * EPL;
    int idxv = 0;

#define ACC(ARR, S)                                                         \
    {                                                                       \
        const unsigned short* r_ = Fh + (size_t)(S) * STRIDE + lb;          \
        if constexpr (EPL == 8) {                                           \
            u16x8 v_ = *(const u16x8*)r_;                                   \
            _Pragma("unroll")                                               \
            for (int j_ = 0; j_ < 8; ++j_) ARR[j_] += b2f(v_[j_]);          \
        } else {                                                            \
            u16x4 v_ = *(const u16x4*)r_;                                   \
            _Pragma("unroll")                                               \
            for (int j_ = 0; j_ < 4; ++j_) ARR[j_] += b2f(v_[j_]);          \
        }                                                                   \
    }

    for (int i = 0; i < deg; i += 4) {
        const int b = i & 63;
        if (b == 0) idxv = (beg + i + lane < end) ? esrc[beg + i + lane] : 0;
        const int s0 = __shfl(idxv, b);
        const int s1 = __shfl(idxv, b + 1);
        const int s2 = __shfl(idxv, b + 2);
        const int s3 = __shfl(idxv, b + 3);
        ACC(a0, s0);
        if (i + 1 < deg) ACC(a1, s1);
        if (i + 2 < deg) ACC(a2, s2);
        if (i + 3 < deg) ACC(a3, s3);
    }
#undef ACC

    unsigned short* op = Ah + (size_t)node * STRIDE + lb;
    if constexpr (EPL == 8) {
        u16x8 h;
#pragma unroll
        for (int j = 0; j < 8; ++j) h[j] = f2b(a0[j] + a1[j] + a2[j] + a3[j]);
        __builtin_nontemporal_store(h, (u16x8*)op);
    } else {
        u16x4 h;
#pragma unroll
        for (int j = 0; j < 4; ++j) h[j] = f2b(a0[j] + a1[j] + a2[j] + a3[j]);
        __builtin_nontemporal_store(h, (u16x4*)op);
    }
}

// ---------------- concat-K MFMA GEMM, counted-vmcnt 2-buffer pipeline ----------------
// out = Acat @ Bcat^T + bias.  Acat: bf16 [M_PAD][K], Bcat: bf16 [512][K].
// Tile 128x128, BK=32, 4 waves, 2x16KB LDS.  Per k-iter:
//   STAGE(next buf)                 (4 global_load_lds / thread, stay in flight)
//   s_waitcnt vmcnt(4); s_barrier   (previous iter's loads landed, all waves)
//   compute(cur buf)                (ds_read + 32 MFMA)
//   s_barrier                       (everyone done reading cur before overwrite)
// FINAL=1: write f32 out.  FINAL=0: write bf16 pre-activation.

template <int FINAL>
__global__ __launch_bounds__(256, 4) void gemm_mfma_kernel(
    const unsigned short* __restrict__ A, const unsigned short* __restrict__ B,
    const float* __restrict__ bias, float* __restrict__ outF,
    unsigned short* __restrict__ pre, int K) {
    __shared__ unsigned short S[2 * 8192];  // 2 buf x {A,B} x 128x32 bf16 = 32 KB
    const int bm = blockIdx.y * 128;
    const int bn = blockIdx.x * 128;
    const int tid = threadIdx.x;
    const int l = tid & 63;
    const int w = tid >> 6;
    const int wr = (w >> 1) * 64;
    const int wc = (w & 1) * 64;
    const int arow = l >> 2;
    const int acol = (l & 3) * 8;

    const unsigned short* gA = A + (size_t)(bm + arow) * K + acol;
    const unsigned short* gB = B + (size_t)(bn + arow) * K + acol;

    f32x4 acc[4][4];
#pragma unroll
    for (int m = 0; m < 4; ++m)
#pragma unroll
        for (int n = 0; n < 4; ++n) acc[m][n] = (f32x4){0.f, 0.f, 0.f, 0.f};

    const int aoff = (wr + (l & 15)) * 32 + (l >> 4) * 8;
    const int woff = (wc + (l & 15)) * 32 + (l >> 4) * 8;
    const int ktiles = K >> 5;

    auto STAGE = [&](int buf, int kt) {
        unsigned short* lb = &S[buf * 8192];
#pragma unroll
        for (int i = 0; i < 2; ++i) {
            const int c = w * 2 + i;  // 16-row chunk, 0..7
            __builtin_amdgcn_global_load_lds(
                (const __attribute__((address_space(1))) void*)(gA + (size_t)(c * 16) * K + kt * 32),
                (__attribute__((address_space(3))) void*)(lb + c * 512), 16, 0, 0);
            __builtin_amdgcn_global_load_lds(
                (const __attribute__((address_space(1))) void*)(gB + (size_t)(c * 16) * K + kt * 32),
                (__attribute__((address_space(3))) void*)(lb + 4096 + c * 512), 16, 0, 0);
        }
    };

    auto COMPUTE = [&](int sb) {
        bf16x8 af[4], wf[4];
#pragma unroll
        for (int m = 0; m < 4; ++m)
            af[m] = *(const bf16x8*)&S[sb + aoff + m * 512];
#pragma unroll
        for (int n = 0; n < 4; ++n)
            wf[n] = *(const bf16x8*)&S[sb + 4096 + woff + n * 512];
#pragma unroll
        for (int m = 0; m < 4; ++m)
#pragma unroll
            for (int n = 0; n < 4; ++n)
                acc[m][n] = __builtin_amdgcn_mfma_f32_16x16x32_bf16(af[m], wf[n], acc[m][n], 0, 0, 0);
    };

    STAGE(0, 0);
    for (int kt = 0; kt < ktiles - 1; ++kt) {
        STAGE((kt + 1) & 1, kt + 1);
        asm volatile("s_waitcnt vmcnt(4)" ::: "memory");  // cur buf's loads landed
        __builtin_amdgcn_s_barrier();                      // ...for ALL waves
        __builtin_amdgcn_sched_barrier(0);                 // keep ds_reads below
        COMPUTE((kt & 1) * 8192);
        __builtin_amdgcn_s_barrier();                      // reads done before overwrite
    }
    asm volatile("s_waitcnt vmcnt(0)" ::: "memory");
    __builtin_amdgcn_s_barrier();
    __builtin_amdgcn_sched_barrier(0);
    COMPUTE(((ktiles - 1) & 1) * 8192);

    const int r0 = bm + wr + (l >> 4) * 4;
    const int c0 = bn + wc + (l & 15);
#pragma unroll
    for (int n = 0; n < 4; ++n) {
        const float bv = bias[c0 + n * 16];
#pragma unroll
        for (int m = 0; m < 4; ++m) {
#pragma unroll
            for (int j = 0; j < 4; ++j) {
                int gr = r0 + m * 16 + j;
                if (gr < N_NODES) {
                    float val = acc[m][n][j] + bv;
                    if constexpr (FINAL)
                        __builtin_nontemporal_store(val, &outF[(size_t)gr * HID + c0 + n * 16]);
                    else
                        __builtin_nontemporal_store(f2b(val), &pre[(size_t)gr * HID + c0 + n * 16]);
                }
            }
        }
    }
}

// ---------------- row L2-normalize + ELU (wave-per-row) ----------------
// FINAL=0: read bf16 preact [M][512], write bf16 feat into Fh (stride 1024).
// FINAL=1: read f32 outF, write f32 outF.

template <int FINAL>
__global__ __launch_bounds__(256) void norm_elu_kernel(const void* __restrict__ inp,
                                                       float* __restrict__ outF,
                                                       unsigned short* __restrict__ Fh) {
    const int wid = threadIdx.x >> 6;
    const int lane = threadIdx.x & 63;
    const int row = blockIdx.x * 4 + wid;
    if (row >= N_NODES) return;
    float r[8];
    if constexpr (FINAL) {
        const float* p = (const float*)inp + (size_t)row * HID + lane * 8;
        float4 v0 = *(const float4*)p;
        float4 v1 = *(const float4*)(p + 4);
        r[0] = v0.x; r[1] = v0.y; r[2] = v0.z; r[3] = v0.w;
        r[4] = v1.x; r[5] = v1.y; r[6] = v1.z; r[7] = v1.w;
    } else {
        const unsigned short* p = (const unsigned short*)inp + (size_t)row * HID + lane * 8;
        u16x8 v = *(const u16x8*)p;
#pragma unroll
        for (int j = 0; j < 8; ++j) r[j] = b2f(v[j]);
    }
    float ss = 0.f;
#pragma unroll
    for (int j = 0; j < 8; ++j) ss += r[j] * r[j];
#pragma unroll
    for (int o = 32; o > 0; o >>= 1) ss += __shfl_xor(ss, o);
    float inv = 1.f / fmaxf(sqrtf(ss), 1e-12f);
#pragma unroll
    for (int j = 0; j < 8; ++j) {
        r[j] *= inv;
        r[j] = r[j] > 0.f ? r[j] : expm1f(r[j]);
    }
    if constexpr (FINAL) {
        float* q = outF + (size_t)row * HID + lane * 8;
        *(float4*)q = make_float4(r[0], r[1], r[2], r[3]);
        *(float4*)(q + 4) = make_float4(r[4], r[5], r[6], r[7]);
    } else {
        unsigned short* q = Fh + (size_t)row * 1024 + lane * 8;
        u16x8 h;
#pragma unroll
        for (int j = 0; j < 8; ++j) h[j] = f2b(r[j]);
        *(u16x8*)q = h;
    }
}

// ---------------- launch ----------------

extern "C" void kernel_launch(void* const* d_in, const int* in_sizes, int n_in,
                              void* d_out, int out_size, void* d_ws, size_t ws_size,
                              hipStream_t stream) {
    const float* x    = (const float*)d_in[0];
    const void*  eidx = d_in[1];
    const float* Wl0 = (const float*)d_in[2];
    const float* bl0 = (const float*)d_in[3];
    const float* Wr0 = (const float*)d_in[4];
    const float* Wl1 = (const float*)d_in[5];
    const float* bl1 = (const float*)d_in[6];
    const float* Wr1 = (const float*)d_in[7];
    const float* Wl2 = (const float*)d_in[8];
    const float* bl2 = (const float*)d_in[9];
    const float* Wr2 = (const float*)d_in[10];
    float* outF = (float*)d_out;
    unsigned short* preB = (unsigned short*)d_out;  // bf16 preact scratch (layers 1-2)

    char* ws = (char*)d_ws;
    size_t o = 0;
    auto alloc = [&](size_t bytes) { void* p = ws + o; o += (bytes + 255) & ~(size_t)255; return p; };

    // Concat activation planes: Cat1 [M][512] (agg256|feat256), Cat2 [M][1024]
    unsigned short* Cat1 = (unsigned short*)alloc((size_t)M_PAD * 512 * 2);
    unsigned short* Cat2 = (unsigned short*)alloc((size_t)M_PAD * 1024 * 2);

    unsigned short* Wcat0 = (unsigned short*)alloc(512 * 512 * 2);
    unsigned short* Wcat1 = (unsigned short*)alloc(512 * 1024 * 2);
    unsigned short* Wcat2 = (unsigned short*)alloc(512 * 1024 * 2);

    // counts and cursor MUST be one contiguous block (R2/R3 lesson: 256B alloc
    // rounding left cursor tail poisoned -> OOB writes -> GPU fault).
    int* counts   = (int*)alloc((size_t)2 * N_NODES * 4);
    int* cursor   = counts + N_NODES;
    int* offsets  = (int*)alloc((size_t)(N_NODES + 1) * 4);
    int* edge_src = (int*)alloc((size_t)N_EDGES * 4);
    int* flag     = (int*)alloc(256);

    // ---- CSR build ----
    zero_kernel<<<(2 * N_NODES + 255) / 256, 256, 0, stream>>>(counts, 2 * N_NODES);
    detect_kernel<<<1, 64, 0, stream>>>((const int*)eidx, flag);
    hist_kernel<<<(N_EDGES + 255) / 256, 256, 0, stream>>>(eidx, flag, counts);
    scan_kernel<<<1, 1024, 0, stream>>>(counts, offsets);
    fill_kernel<<<(N_EDGES + 255) / 256, 256, 0, stream>>>(eidx, flag, offsets, cursor, edge_src);

    // ---- conversions ----
    xconv_kernel<<<(M_PAD * 64 + 255) / 256, 256, 0, stream>>>(x, Cat1);
    wconv_kernel<<<512, 128, 0, stream>>>(Wl0, Wcat0, 256, 512, 0);
    wconv_kernel<<<512, 128, 0, stream>>>(Wr0, Wcat0, 256, 512, 256);
    wconv_kernel<<<512, 128, 0, stream>>>(Wl1, Wcat1, 512, 1024, 0);
    wconv_kernel<<<512, 128, 0, stream>>>(Wr1, Wcat1, 512, 1024, 512);
    wconv_kernel<<<512, 128, 0, stream>>>(Wl2, Wcat2, 512, 1024, 0);
    wconv_kernel<<<512, 128, 0, stream>>>(Wr2, Wcat2, 512, 1024, 512);

    dim3 ggrid(4, M_PAD / 128);           // (512/128, 391)
    const int ngrid = (N_NODES + 3) / 4;  // 4 rows per 256-block

    // layer 1 (feat 256): Cat1 = agg|x, K=512
    aggregate_kernel<4><<<ngrid, 256, 0, stream>>>(Cat1 + 256, offsets, edge_src, Cat1);
    gemm_mfma_kernel<0><<<ggrid, 256, 0, stream>>>(Cat1, Wcat0, bl0, nullptr, preB, 512);
    norm_elu_kernel<0><<<ngrid, 256, 0, stream>>>(preB, nullptr, Cat2 + 512);

    // layer 2 (feat 512): Cat2 = agg|feat, K=1024
    aggregate_kernel<8><<<ngrid, 256, 0, stream>>>(Cat2 + 512, offsets, edge_src, Cat2);
    gemm_mfma_kernel<0><<<ggrid, 256, 0, stream>>>(Cat2, Wcat1, bl1, nullptr, preB, 1024);
    norm_elu_kernel<0><<<ngrid, 256, 0, stream>>>(preB, nullptr, Cat2 + 512);

    // layer 3 (feat 512): final -> f32
    aggregate_kernel<8><<<ngrid, 256, 0, stream>>>(Cat2 + 512, offsets, edge_src, Cat2);
    gemm_mfma_kernel<1><<<ggrid, 256, 0, stream>>>(Cat2, Wcat2, bl2, outF, nullptr, 1024);
    norm_elu_kernel<1><<<ngrid, 256, 0, stream>>>(outF, outF, nullptr);

    (void)in_sizes; (void)n_in; (void)out_size; (void)ws_size;
}

// Round 9
// 784.810 us; speedup vs baseline: 1.0794x; 1.0794x over previous
//
#include <hip/hip_runtime.h>
#include <math.h>

#define N_NODES 50000
#define M_PAD   50048   // 391 * 128
#define N_EDGES 800000
#define HID 512

typedef short bf16x8 __attribute__((ext_vector_type(8)));
typedef float f32x4  __attribute__((ext_vector_type(4)));
typedef unsigned short u16x4 __attribute__((ext_vector_type(4)));
typedef unsigned short u16x8 __attribute__((ext_vector_type(8)));

__device__ inline float b2f(unsigned short u) {
    union { unsigned int i; float f; } v; v.i = ((unsigned int)u) << 16; return v.f;
}
__device__ inline unsigned short f2b(float f) {
    union { float f; unsigned int i; } v; v.f = f;
    unsigned int r = v.i + 0x7FFFu + ((v.i >> 16) & 1u);
    return (unsigned short)(r >> 16);
}

// ---------------- CSR build ----------------

__global__ void zero_kernel(int* __restrict__ p, int n) {
    int i = blockIdx.x * blockDim.x + threadIdx.x;
    if (i < n) p[i] = 0;
}

__global__ void detect_kernel(const int* __restrict__ e, int* __restrict__ flag) {
    if (blockIdx.x == 0 && threadIdx.x == 0) {
        int is64 = 1;
        for (int i = 0; i < 16; ++i)
            if (e[2 * i + 1] != 0) is64 = 0;
        *flag = is64;
    }
}

__global__ void hist_kernel(const void* __restrict__ eidx, const int* __restrict__ flag,
                            int* __restrict__ counts) {
    int e = blockIdx.x * blockDim.x + threadIdx.x;
    if (e >= N_EDGES) return;
    int is64 = *flag;
    int d;
    if (is64) d = (int)((const long long*)eidx)[N_EDGES + e];
    else      d = ((const int*)eidx)[N_EDGES + e];
    atomicAdd(&counts[d], 1);
}

__global__ __launch_bounds__(1024) void scan_kernel(const int* __restrict__ counts,
                                                    int* __restrict__ offsets) {
    __shared__ int sums[1024];
    int t = threadIdx.x;
    const int CH = (N_NODES + 1023) / 1024;  // 49
    int lo = t * CH;
    int hi = min(lo + CH, N_NODES);
    int s = 0;
    for (int i = lo; i < hi; ++i) s += counts[i];
    sums[t] = s;
    __syncthreads();
    for (int off = 1; off < 1024; off <<= 1) {
        int v = 0;
        if (t >= off) v = sums[t - off];
        __syncthreads();
        sums[t] += v;
        __syncthreads();
    }
    int excl = (t == 0) ? 0 : sums[t - 1];
    for (int i = lo; i < hi; ++i) { offsets[i] = excl; excl += counts[i]; }
    if (t == 1023) offsets[N_NODES] = excl;
}

__global__ void fill_kernel(const void* __restrict__ eidx, const int* __restrict__ flag,
                            const int* __restrict__ offsets, int* __restrict__ cursor,
                            int* __restrict__ edge_src) {
    int e = blockIdx.x * blockDim.x + threadIdx.x;
    if (e >= N_EDGES) return;
    int is64 = *flag;
    int s, d;
    if (is64) {
        const long long* p = (const long long*)eidx;
        s = (int)p[e];
        d = (int)p[N_EDGES + e];
    } else {
        const int* p = (const int*)eidx;
        s = p[e];
        d = p[N_EDGES + e];
    }
    int pos = atomicAdd(&cursor[d], 1);
    edge_src[offsets[d] + pos] = s;
}

// ---------------- conversions ----------------

// x (f32 [N,256]) -> bf16 into feat-half of Cat1 ([M][512], cols 256..512)
__global__ __launch_bounds__(256) void xconv_kernel(const float* __restrict__ x,
                                                    unsigned short* __restrict__ cat1) {
    int id = blockIdx.x * 256 + threadIdx.x;
    if (id >= M_PAD * 64) return;
    int row = id >> 6;
    int c = (id & 63) * 4;
    float4 v = make_float4(0.f, 0.f, 0.f, 0.f);
    if (row < N_NODES) v = *(const float4*)(x + (size_t)row * 256 + c);
    ushort4 h;
    h.x = f2b(v.x); h.y = f2b(v.y); h.z = f2b(v.z); h.w = f2b(v.w);
    *(ushort4*)(cat1 + (size_t)row * 512 + 256 + c) = h;
}

// W (f32 [K,512]) -> transposed bf16 into Wcat[n][off + k], row stride ktot
__global__ __launch_bounds__(128) void wconv_kernel(const float* __restrict__ W,
                                                    unsigned short* __restrict__ T,
                                                    int K, int ktot, int off) {
    int n = blockIdx.x;  // 0..511
    for (int k = threadIdx.x; k < K; k += 128)
        T[(size_t)n * ktot + off + k] = f2b(W[(size_t)k * HID + n]);
}

// ---------------- aggregate: wave-per-node, 8 loads in flight ----------------
// Feat width W = EPL*64, row stride 2W (halves of the concat plane).

template <int EPL>
__global__ __launch_bounds__(256) void aggregate_kernel(const unsigned short* __restrict__ Fh,
                                                        const int* __restrict__ off,
                                                        const int* __restrict__ esrc,
                                                        unsigned short* __restrict__ Ah) {
    const int STRIDE = 2 * EPL * 64;
    const int wid = threadIdx.x >> 6;
    const int lane = threadIdx.x & 63;
    const int node = blockIdx.x * 4 + wid;
    if (node >= N_NODES) return;
    const int beg = off[node], end = off[node + 1];
    const int deg = end - beg;
    const int lb = lane * EPL;
    using VecT = typename std::conditional<EPL == 8, u16x8, u16x4>::type;

    float a0[EPL], a1[EPL];
#pragma unroll
    for (int j = 0; j < EPL; ++j) { a0[j] = 0.f; a1[j] = 0.f; }

    int idxv = 0;
    int i = 0;
    // main: 8 rows in flight per pass
    for (; i + 8 <= deg; i += 8) {
        const int b = i & 63;
        if (b == 0) idxv = (beg + i + lane < end) ? esrc[beg + i + lane] : 0;
        int s[8];
#pragma unroll
        for (int k = 0; k < 8; ++k) s[k] = __shfl(idxv, b + k);
        VecT v[8];
#pragma unroll
        for (int k = 0; k < 8; ++k)
            v[k] = *(const VecT*)(Fh + (size_t)s[k] * STRIDE + lb);
#pragma unroll
        for (int k = 0; k < 8; ++k) {
#pragma unroll
            for (int j = 0; j < EPL; ++j) {
                if (k & 1) a1[j] += b2f(v[k][j]);
                else       a0[j] += b2f(v[k][j]);
            }
        }
    }
    // tail (< 8 edges)
    for (; i < deg; ++i) {
        const int b = i & 63;
        if (b == 0) idxv = (beg + i + lane < end) ? esrc[beg + i + lane] : 0;
        const int s = __shfl(idxv, b);
        VecT v = *(const VecT*)(Fh + (size_t)s * STRIDE + lb);
#pragma unroll
        for (int j = 0; j < EPL; ++j) a0[j] += b2f(v[j]);
    }

    unsigned short* op = Ah + (size_t)node * STRIDE + lb;
    VecT h;
#pragma unroll
    for (int j = 0; j < EPL; ++j) h[j] = f2b(a0[j] + a1[j]);
    __builtin_nontemporal_store(h, (VecT*)op);
}

// ---------------- concat-K MFMA GEMM: 128x256 tile, 8 waves, 2-phase dbuf ----------------
// out = Acat @ Bcat^T + bias.  Acat: bf16 [M_PAD][K], Bcat: bf16 [512][K].
// BK=32.  LDS 2 x (A 8KB + B 16KB) = 48 KB -> 3 blocks/CU.
// A re-read only 2x (BN=256); B panel (512KB) L2-resident per XCD.
// Staging: 3 x 16B global_load_lds per thread; 16 MFMA per wave per k-iter.
// FINAL=1: f32 out.  FINAL=0: bf16 pre-activation (plain stores: norm reads next).

template <int FINAL>
__global__ __launch_bounds__(512, 2) void gemm_mfma_kernel(
    const unsigned short* __restrict__ A, const unsigned short* __restrict__ B,
    const float* __restrict__ bias, float* __restrict__ outF,
    unsigned short* __restrict__ pre, int K) {
    __shared__ unsigned short S[2 * 12288];  // u16 elems: 2 x (4096 A + 8192 B)
    const int bm = blockIdx.y * 128;
    const int bn = blockIdx.x * 256;
    const int tid = threadIdx.x;
    const int l = tid & 63;
    const int w = tid >> 6;          // 0..7
    const int wr = (w >> 2) * 64;    // 2 row-waves
    const int wc = (w & 3) * 64;     // 4 col-waves

    // staging addresses: A 1 load, B 2 loads per thread
    const int se = (tid >> 2) * 32 + (tid & 3) * 8;  // LDS elem offset within a tile
    const unsigned short* gA  = A + (size_t)(bm + (tid >> 2)) * K + (tid & 3) * 8;
    const unsigned short* gB0 = B + (size_t)(bn + (tid >> 2)) * K + (tid & 3) * 8;
    const unsigned short* gB1 = B + (size_t)(bn + 128 + (tid >> 2)) * K + (tid & 3) * 8;

    f32x4 acc[4][4];
#pragma unroll
    for (int m = 0; m < 4; ++m)
#pragma unroll
        for (int n = 0; n < 4; ++n) acc[m][n] = (f32x4){0.f, 0.f, 0.f, 0.f};

    const int aoff = (wr + (l & 15)) * 32 + (l >> 4) * 8;
    const int woff = 4096 + (wc + (l & 15)) * 32 + (l >> 4) * 8;
    const int ktiles = K >> 5;

    auto STAGE = [&](int buf, int kt) {
        unsigned short* lb = &S[buf * 12288];
        __builtin_amdgcn_global_load_lds(
            (const __attribute__((address_space(1))) void*)(gA + kt * 32),
            (__attribute__((address_space(3))) void*)(lb + se), 16, 0, 0);
        __builtin_amdgcn_global_load_lds(
            (const __attribute__((address_space(1))) void*)(gB0 + kt * 32),
            (__attribute__((address_space(3))) void*)(lb + 4096 + se), 16, 0, 0);
        __builtin_amdgcn_global_load_lds(
            (const __attribute__((address_space(1))) void*)(gB1 + kt * 32),
            (__attribute__((address_space(3))) void*)(lb + 8192 + se), 16, 0, 0);
    };

    STAGE(0, 0);
    __syncthreads();

    for (int kt = 0; kt < ktiles; ++kt) {
        if (kt + 1 < ktiles) STAGE((kt + 1) & 1, kt + 1);  // prefetch next
        const int sb = (kt & 1) * 12288;

        bf16x8 af[4], wf[4];
#pragma unroll
        for (int m = 0; m < 4; ++m)
            af[m] = *(const bf16x8*)&S[sb + aoff + m * 512];
#pragma unroll
        for (int n = 0; n < 4; ++n)
            wf[n] = *(const bf16x8*)&S[sb + woff + n * 512];
#pragma unroll
        for (int m = 0; m < 4; ++m)
#pragma unroll
            for (int n = 0; n < 4; ++n)
                acc[m][n] = __builtin_amdgcn_mfma_f32_16x16x32_bf16(af[m], wf[n], acc[m][n], 0, 0, 0);
        __syncthreads();  // drains vmcnt (prefetch landed) + protects buf just read
    }

    const int r0 = bm + wr + (l >> 4) * 4;
    const int c0 = bn + wc + (l & 15);
#pragma unroll
    for (int n = 0; n < 4; ++n) {
        const float bv = bias[c0 + n * 16];
#pragma unroll
        for (int m = 0; m < 4; ++m) {
#pragma unroll
            for (int j = 0; j < 4; ++j) {
                int gr = r0 + m * 16 + j;
                if (gr < N_NODES) {
                    float val = acc[m][n][j] + bv;
                    if constexpr (FINAL)
                        outF[(size_t)gr * HID + c0 + n * 16] = val;
                    else
                        pre[(size_t)gr * HID + c0 + n * 16] = f2b(val);
                }
            }
        }
    }
}

// ---------------- row L2-normalize + ELU (wave-per-row) ----------------
// FINAL=0: read bf16 preact [M][512], write bf16 feat into Fh (stride 1024).
// FINAL=1: read f32 outF, write f32 outF.

template <int FINAL>
__global__ __launch_bounds__(256) void norm_elu_kernel(const void* __restrict__ inp,
                                                       float* __restrict__ outF,
                                                       unsigned short* __restrict__ Fh) {
    const int wid = threadIdx.x >> 6;
    const int lane = threadIdx.x & 63;
    const int row = blockIdx.x * 4 + wid;
    if (row >= N_NODES) return;
    float r[8];
    if constexpr (FINAL) {
        const float* p = (const float*)inp + (size_t)row * HID + lane * 8;
        float4 v0 = *(const float4*)p;
        float4 v1 = *(const float4*)(p + 4);
        r[0] = v0.x; r[1] = v0.y; r[2] = v0.z; r[3] = v0.w;
        r[4] = v1.x; r[5] = v1.y; r[6] = v1.z; r[7] = v1.w;
    } else {
        const unsigned short* p = (const unsigned short*)inp + (size_t)row * HID + lane * 8;
        u16x8 v = *(const u16x8*)p;
#pragma unroll
        for (int j = 0; j < 8; ++j) r[j] = b2f(v[j]);
    }
    float ss = 0.f;
#pragma unroll
    for (int j = 0; j < 8; ++j) ss += r[j] * r[j];
#pragma unroll
    for (int o = 32; o > 0; o >>= 1) ss += __shfl_xor(ss, o);
    float inv = 1.f / fmaxf(sqrtf(ss), 1e-12f);
#pragma unroll
    for (int j = 0; j < 8; ++j) {
        r[j] *= inv;
        r[j] = r[j] > 0.f ? r[j] : expm1f(r[j]);
    }
    if constexpr (FINAL) {
        float* q = outF + (size_t)row * HID + lane * 8;
        *(float4*)q = make_float4(r[0], r[1], r[2], r[3]);
        *(float4*)(q + 4) = make_float4(r[4], r[5], r[6], r[7]);
    } else {
        unsigned short* q = Fh + (size_t)row * 1024 + lane * 8;
        u16x8 h;
#pragma unroll
        for (int j = 0; j < 8; ++j) h[j] = f2b(r[j]);
        *(u16x8*)q = h;
    }
}

// ---------------- launch ----------------

extern "C" void kernel_launch(void* const* d_in, const int* in_sizes, int n_in,
                              void* d_out, int out_size, void* d_ws, size_t ws_size,
                              hipStream_t stream) {
    const float* x    = (const float*)d_in[0];
    const void*  eidx = d_in[1];
    const float* Wl0 = (const float*)d_in[2];
    const float* bl0 = (const float*)d_in[3];
    const float* Wr0 = (const float*)d_in[4];
    const float* Wl1 = (const float*)d_in[5];
    const float* bl1 = (const float*)d_in[6];
    const float* Wr1 = (const float*)d_in[7];
    const float* Wl2 = (const float*)d_in[8];
    const float* bl2 = (const float*)d_in[9];
    const float* Wr2 = (const float*)d_in[10];
    float* outF = (float*)d_out;
    unsigned short* preB = (unsigned short*)d_out;  // bf16 preact scratch (layers 1-2)

    char* ws = (char*)d_ws;
    size_t o = 0;
    auto alloc = [&](size_t bytes) { void* p = ws + o; o += (bytes + 255) & ~(size_t)255; return p; };

    // Concat activation planes: Cat1 [M][512] (agg256|feat256), Cat2 [M][1024]
    unsigned short* Cat1 = (unsigned short*)alloc((size_t)M_PAD * 512 * 2);
    unsigned short* Cat2 = (unsigned short*)alloc((size_t)M_PAD * 1024 * 2);

    unsigned short* Wcat0 = (unsigned short*)alloc(512 * 512 * 2);
    unsigned short* Wcat1 = (unsigned short*)alloc(512 * 1024 * 2);
    unsigned short* Wcat2 = (unsigned short*)alloc(512 * 1024 * 2);

    // counts and cursor MUST be one contiguous block (R2/R3 lesson: 256B alloc
    // rounding left cursor tail poisoned -> OOB writes -> GPU fault).
    int* counts   = (int*)alloc((size_t)2 * N_NODES * 4);
    int* cursor   = counts + N_NODES;
    int* offsets  = (int*)alloc((size_t)(N_NODES + 1) * 4);
    int* edge_src = (int*)alloc((size_t)N_EDGES * 4);
    int* flag     = (int*)alloc(256);

    // ---- CSR build ----
    zero_kernel<<<(2 * N_NODES + 255) / 256, 256, 0, stream>>>(counts, 2 * N_NODES);
    detect_kernel<<<1, 64, 0, stream>>>((const int*)eidx, flag);
    hist_kernel<<<(N_EDGES + 255) / 256, 256, 0, stream>>>(eidx, flag, counts);
    scan_kernel<<<1, 1024, 0, stream>>>(counts, offsets);
    fill_kernel<<<(N_EDGES + 255) / 256, 256, 0, stream>>>(eidx, flag, offsets, cursor, edge_src);

    // ---- conversions ----
    xconv_kernel<<<(M_PAD * 64 + 255) / 256, 256, 0, stream>>>(x, Cat1);
    wconv_kernel<<<512, 128, 0, stream>>>(Wl0, Wcat0, 256, 512, 0);
    wconv_kernel<<<512, 128, 0, stream>>>(Wr0, Wcat0, 256, 512, 256);
    wconv_kernel<<<512, 128, 0, stream>>>(Wl1, Wcat1, 512, 1024, 0);
    wconv_kernel<<<512, 128, 0, stream>>>(Wr1, Wcat1, 512, 1024, 512);
    wconv_kernel<<<512, 128, 0, stream>>>(Wl2, Wcat2, 512, 1024, 0);
    wconv_kernel<<<512, 128, 0, stream>>>(Wr2, Wcat2, 512, 1024, 512);

    dim3 ggrid(2, M_PAD / 128);           // (512/256, 391)
    const int ngrid = (N_NODES + 3) / 4;  // 4 rows per 256-block

    // layer 1 (feat 256): Cat1 = agg|x, K=512
    aggregate_kernel<4><<<ngrid, 256, 0, stream>>>(Cat1 + 256, offsets, edge_src, Cat1);
    gemm_mfma_kernel<0><<<ggrid, 512, 0, stream>>>(Cat1, Wcat0, bl0, nullptr, preB, 512);
    norm_elu_kernel<0><<<ngrid, 256, 0, stream>>>(preB, nullptr, Cat2 + 512);

    // layer 2 (feat 512): Cat2 = agg|feat, K=1024
    aggregate_kernel<8><<<ngrid, 256, 0, stream>>>(Cat2 + 512, offsets, edge_src, Cat2);
    gemm_mfma_kernel<0><<<ggrid, 512, 0, stream>>>(Cat2, Wcat1, bl1, nullptr, preB, 1024);
    norm_elu_kernel<0><<<ngrid, 256, 0, stream>>>(preB, nullptr, Cat2 + 512);

    // layer 3 (feat 512): final -> f32
    aggregate_kernel<8><<<ngrid, 256, 0, stream>>>(Cat2 + 512, offsets, edge_src, Cat2);
    gemm_mfma_kernel<1><<<ggrid, 512, 0, stream>>>(Cat2, Wcat2, bl2, outF, nullptr, 1024);
    norm_elu_kernel<1><<<ngrid, 256, 0, stream>>>(outF, outF, nullptr);

    (void)in_sizes; (void)n_in; (void)out_size; (void)ws_size;
}